// Round 4
// baseline (291.187 us; speedup 1.0000x reference)
//
#include <hip/hip_runtime.h>
#include <cstdint>

// Problem: B=4, S=2048, D_MODEL=1024, H=16, depth=64.
// Pipeline: pack x->bf16 + pack/transpose W->bf16 [N][K] (one launch);
// QKV GEMM (bf16 MFMA, fp32 acc, single-barrier double-buffered K-loop) ->
// Q[bh,s,d] (pre-scaled by log2e/8), K[bh,s,d], Vt[bh,d,s'] key-permuted;
// flash attention (no-max softmax, P in registers, row-sums via ones-MFMA);
// out GEMM -> fp32.

typedef __bf16 bf16x8 __attribute__((ext_vector_type(8)));
typedef float f32x4 __attribute__((ext_vector_type(4)));
typedef int i32x4 __attribute__((ext_vector_type(4)));

#define CEXP 0.18033688011112042f  // (1/8) * log2(e), folded into Q

__device__ __forceinline__ unsigned short f2bf(float f) {
  union { float f; unsigned int u; } v; v.f = f;
  unsigned int r = v.u + 0x7FFFu + ((v.u >> 16) & 1u);  // RNE
  return (unsigned short)(r >> 16);
}
__device__ __forceinline__ unsigned int fbits(float f) {
  union { float f; unsigned int u; } v; v.f = f; return v.u;
}

// pack two f32 -> one int holding (bf16(b)<<16)|bf16(a)
__device__ __forceinline__ int pkbf16(float a, float b) {
#if __has_builtin(__builtin_amdgcn_cvt_pk_bf16_f32)
  auto r = __builtin_amdgcn_cvt_pk_bf16_f32(a, b);  // lo=cvt(a), hi=cvt(b), RNE
  return __builtin_bit_cast(int, r);
#else
  return (int)__builtin_amdgcn_perm(fbits(b) + 0x8000u, fbits(a) + 0x8000u, 0x07060302u);
#endif
}

// async global->LDS, 16B per lane. LDS dest = wave-uniform base + lane*16.
__device__ __forceinline__ void gl_lds16(const void* g, void* l) {
  __builtin_amdgcn_global_load_lds(
      (const __attribute__((address_space(1))) void*)(unsigned long long)g,
      (__attribute__((address_space(3))) void*)(unsigned int)(unsigned long long)l,
      16, 0, 0);
}

// ---------------- pack x (fp32 -> bf16) + pack/transpose weights ----------------
__global__ __launch_bounds__(256) void pack_all_kernel(const float* __restrict__ x,
                                                       const float* __restrict__ wq,
                                                       const float* __restrict__ wk,
                                                       const float* __restrict__ wv,
                                                       const float* __restrict__ wo,
                                                       unsigned short* __restrict__ xb,
                                                       unsigned short* __restrict__ wqkvt,
                                                       unsigned short* __restrict__ wot) {
  int bid = blockIdx.x;
  if (bid < 8192) {  // pack x
    int i = (bid * 256 + threadIdx.x) * 4;
    float4 v = *(const float4*)(x + i);
    unsigned int lo = (unsigned int)f2bf(v.x) | ((unsigned int)f2bf(v.y) << 16);
    unsigned int hi = (unsigned int)f2bf(v.z) | ((unsigned int)f2bf(v.w) << 16);
    uint2 st; st.x = lo; st.y = hi;
    *(uint2*)(xb + i) = st;
    return;
  }
  // pack + transpose weights: Wt[n][k] = w[k][n]
  __shared__ unsigned short T[64 * 66];  // +2 pad: conflict-free
  bid -= 8192;
  int mat = bid >> 8;                    // 0..3 = wq,wk,wv,wo
  int tile = bid & 255;
  int tk = tile >> 4, tn = tile & 15;    // 64x64 tiles
  const float* W = (mat == 0) ? wq : (mat == 1) ? wk : (mat == 2) ? wv : wo;
  int t = threadIdx.x;
#pragma unroll
  for (int p = 0; p < 16; ++p) {
    int e = p * 256 + t;
    int r = e >> 6, c = e & 63;
    T[c * 66 + r] = f2bf(W[(tk * 64 + r) * 1024 + tn * 64 + c]);
  }
  __syncthreads();
  unsigned short* dst = (mat < 3) ? (wqkvt + mat * 1024 * 1024) : wot;
#pragma unroll
  for (int p = 0; p < 16; ++p) {
    int e = p * 256 + t;
    int nn = e >> 6, kk = e & 63;
    dst[(tn * 64 + nn) * 1024 + tk * 64 + kk] = T[nn * 66 + kk];
  }
}

// stage one 128x64 A-tile and 128x64 B-tile (swizzled) via global_load_lds
__device__ __forceinline__ void stage_tile(const unsigned short* __restrict__ Ag,
                                           const unsigned short* __restrict__ Bg,
                                           unsigned short* As, unsigned short* Bs,
                                           int t, int wave) {
#pragma unroll
  for (int p = 0; p < 4; ++p) {
    int s = p * 256 + t;
    int row = s >> 3;
    int cc = (s & 7) ^ (row & 7);
    gl_lds16(Ag + row * 1024 + cc * 8, (void*)(As + (p * 256 + wave * 64) * 8));
    gl_lds16(Bg + row * 1024 + cc * 8, (void*)(Bs + (p * 256 + wave * 64) * 8));
  }
}

// ---------------- GEMM: C[M][N] = A[M][1024] * Bt[N][1024]^T ----------------
// Single-barrier double-buffered K-loop (prefetch flies during compute).
// MODE 0: QKV epilogue (bias + scatter bf16 to Q/K/Vt; Q pre-scaled by CEXP;
//         Vt key order permuted within 64-blocks).  MODE 1: fp32 out + bias.
template <int MODE>
__global__ __launch_bounds__(256) void gemm_bt_kernel(
    const unsigned short* __restrict__ A, const unsigned short* __restrict__ Bt,
    const float* __restrict__ b0, const float* __restrict__ b1, const float* __restrict__ b2,
    unsigned short* __restrict__ Qg, unsigned short* __restrict__ Kg,
    unsigned short* __restrict__ Vtg, float* __restrict__ Of) {
  __shared__ __align__(16) unsigned short S[32768];  // 64KB: [buf][A 8192 | B 8192]
  const int t = threadIdx.x;
  const int lane = t & 63, wave = t >> 6;
  const int l15 = lane & 15, quad = lane >> 4;
  const int wm = wave & 1, wn = wave >> 1;
  const int m0 = blockIdx.x * 128, n0 = blockIdx.y * 128;
  const unsigned short* Ab = A + (size_t)m0 * 1024;
  const unsigned short* Bb = Bt + (size_t)n0 * 1024;

  f32x4 acc[4][4];
#pragma unroll
  for (int i = 0; i < 4; ++i)
#pragma unroll
    for (int j = 0; j < 4; ++j) acc[i][j] = (f32x4){0.f, 0.f, 0.f, 0.f};

  const int Xo0 = ((quad ^ (l15 & 7)) * 8);
  const int Xo1 = (((4 + quad) ^ (l15 & 7)) * 8);

  stage_tile(Ab, Bb, S, S + 8192, t, wave);  // tile 0 -> buf 0

  for (int k0 = 0; k0 < 1024; k0 += 64) {
    const int buf = (k0 >> 6) & 1;
    unsigned short* Sc = S + buf * 16384;
    __syncthreads();  // drains buf's loads (issued one full iteration ago)
    if (k0 < 1024 - 64) {
      unsigned short* Sn = S + (buf ^ 1) * 16384;
      stage_tile(Ab + k0 + 64, Bb + k0 + 64, Sn, Sn + 8192, t, wave);
    }
#pragma unroll
    for (int kc = 0; kc < 2; ++kc) {
      const int Xo = kc ? Xo1 : Xo0;
      bf16x8 af[4], bfr[4];
#pragma unroll
      for (int mi = 0; mi < 4; ++mi)
        af[mi] = *(const bf16x8*)&Sc[(wm * 64 + mi * 16 + l15) * 64 + Xo];
#pragma unroll
      for (int ni = 0; ni < 4; ++ni)
        bfr[ni] = *(const bf16x8*)&Sc[8192 + (wn * 64 + ni * 16 + l15) * 64 + Xo];
#pragma unroll
      for (int mi = 0; mi < 4; ++mi)
#pragma unroll
        for (int ni = 0; ni < 4; ++ni)
          acc[mi][ni] = __builtin_amdgcn_mfma_f32_16x16x32_bf16(af[mi], bfr[ni], acc[mi][ni], 0, 0, 0);
    }
  }

  if (MODE == 0) {
    const int seg = blockIdx.y >> 3;  // 0=Q,1=K,2=V
    const float* bias = (seg == 0) ? b0 : (seg == 1) ? b1 : b2;
    unsigned short* qk = (seg == 0) ? Qg : Kg;
#pragma unroll
    for (int mi = 0; mi < 4; ++mi)
#pragma unroll
      for (int ni = 0; ni < 4; ++ni) {
        int n = n0 + wn * 64 + ni * 16 + l15;
        int nn = n & 1023;
        float bb = bias[nn];
        int h = nn >> 6, d = nn & 63;
#pragma unroll
        for (int r = 0; r < 4; ++r) {
          int m = m0 + wm * 64 + mi * 16 + quad * 4 + r;
          int b = m >> 11, s = m & 2047;
          float val = acc[mi][ni][r] + bb;
          if (seg == 2) {
            // permute key order within 64-blocks so attn's P-register order
            // matches V^T's staged order: pos = kc<<5 | q<<3 | u<<2 | r
            int sp = (s & ~63) | (s & 32) | ((s & 12) << 1) | ((s & 16) >> 2) | (s & 3);
            Vtg[((b * 16 + h) * 64 + d) * 2048 + sp] = f2bf(val);
          } else {
            if (seg == 0) val *= CEXP;  // fold softmax scale * log2(e) into Q
            qk[((b * 16 + h) * 2048 + s) * 64 + d] = f2bf(val);
          }
        }
      }
  } else {
#pragma unroll
    for (int mi = 0; mi < 4; ++mi)
#pragma unroll
      for (int ni = 0; ni < 4; ++ni) {
        int n = n0 + wn * 64 + ni * 16 + l15;
        float bb = b0[n];
#pragma unroll
        for (int r = 0; r < 4; ++r) {
          int m = m0 + wm * 64 + mi * 16 + quad * 4 + r;
          Of[m * 1024 + n] = acc[mi][ni][r] + bb;
        }
      }
  }
}

// ---------------- flash attention (S^T formulation, no-max softmax) ----------------
// grid: 1024 blocks; swizzled to (bh, qt). 4 waves; wave owns 32 q rows.
// Per kt (64 keys): S^T = K*Q^T (C-layout: key=quad*4+r, q=l15);
// p = exp2(s) (scale pre-folded into Q); P^T packed in regs = PV B-operand
// (V^T global key order pre-permuted to match); O^T += V^T * P^T; row-sums l
// accumulated by an extra MFMA with A = all-ones (every lane ends with full l).
__global__ __launch_bounds__(256) void attn_kernel(const unsigned short* __restrict__ Qg,
                                                   const unsigned short* __restrict__ Kg,
                                                   const unsigned short* __restrict__ Vtg,
                                                   unsigned short* __restrict__ Og) {
  __shared__ __align__(16) unsigned short smem[16384];  // 32 KB
  // [0..8191]: Q tile, later K/V buf1 (K@0, V@4096). [8192..]: K/V buf0.
  const int t = threadIdx.x;
  const int lane = t & 63, wave = t >> 6;
  const int l15 = lane & 15, quad = lane >> 4;
  const int bid = blockIdx.x;
  const int bh = (bid & 7) * 8 + (bid >> 7);  // XCD-affinity: same bh -> same XCD
  const int qt = (bid >> 3) & 15;

  const unsigned short* Qh = Qg + (bh * 2048 + qt * 128) * 64;
  const unsigned short* Kh = Kg + bh * 2048 * 64;
  const unsigned short* Vth = Vtg + bh * 64 * 2048;

  // stage Q (128x64, swizzled)
#pragma unroll
  for (int p = 0; p < 4; ++p) {
    int s = p * 256 + t;
    int row = s >> 3, cc = (s & 7) ^ (row & 7);
    gl_lds16(Qh + row * 64 + cc * 8, (void*)(smem + (p * 256 + wave * 64) * 8));
  }
  __syncthreads();

  const int Xo0 = ((quad ^ (l15 & 7)) * 8);
  const int Xo1 = (((4 + quad) ^ (l15 & 7)) * 8);

  // loop-invariant Q fragments (B-operand: lane=q, elems=d)
  bf16x8 qf[2][2];
#pragma unroll
  for (int qi = 0; qi < 2; ++qi) {
    qf[qi][0] = *(const bf16x8*)&smem[(wave * 32 + qi * 16 + l15) * 64 + Xo0];
    qf[qi][1] = *(const bf16x8*)&smem[(wave * 32 + qi * 16 + l15) * 64 + Xo1];
  }

  // stage K/V tile 0 into buf0
#pragma unroll
  for (int p = 0; p < 2; ++p) {
    int s = p * 256 + t;
    int row = s >> 3, cc = (s & 7) ^ (row & 7);
    gl_lds16(Kh + row * 64 + cc * 8, (void*)(smem + 8192 + (p * 256 + wave * 64) * 8));
    gl_lds16(Vth + row * 2048 + cc * 8, (void*)(smem + 12288 + (p * 256 + wave * 64) * 8));
  }

  const f32x4 FZ = (f32x4){0.f, 0.f, 0.f, 0.f};   // persistent zero C-operand
  const int one2 = 0x3F803F80;                    // two bf16 1.0
  const i32x4 onesi = (i32x4){one2, one2, one2, one2};
  const bf16x8 ones = __builtin_bit_cast(bf16x8, onesi);

  f32x4 oacc[4][2];
#pragma unroll
  for (int di = 0; di < 4; ++di)
#pragma unroll
    for (int qi = 0; qi < 2; ++qi) oacc[di][qi] = FZ;
  f32x4 lacc[2];
  lacc[0] = FZ; lacc[1] = FZ;

  for (int kt = 0; kt < 32; ++kt) {
    __syncthreads();  // buf[kt&1] loads drained; prior compute on buf[(kt+1)&1] done
    if (kt + 1 < 32) {
      const unsigned short* Kn = Kh + (kt + 1) * 64 * 64;
      const unsigned short* Vn = Vth + (kt + 1) * 64;
      unsigned short* Kd = smem + (((kt + 1) & 1) ? 0 : 8192);
      unsigned short* Vd = smem + (((kt + 1) & 1) ? 4096 : 12288);
#pragma unroll
      for (int p = 0; p < 2; ++p) {
        int s = p * 256 + t;
        int row = s >> 3, cc = (s & 7) ^ (row & 7);
        gl_lds16(Kn + row * 64 + cc * 8, (void*)(Kd + (p * 256 + wave * 64) * 8));
        gl_lds16(Vn + row * 2048 + cc * 8, (void*)(Vd + (p * 256 + wave * 64) * 8));
      }
    }
    const unsigned short* Ks = smem + ((kt & 1) ? 0 : 8192);
    const unsigned short* Vs = smem + ((kt & 1) ? 4096 : 12288);

    // S^T = K * Q^T  (kc=0 uses zero C-operand: no per-kt acc zeroing)
    f32x4 sacc[4][2];
    {
      bf16x8 kf[4];
#pragma unroll
      for (int ki = 0; ki < 4; ++ki)
        kf[ki] = *(const bf16x8*)&Ks[(ki * 16 + l15) * 64 + Xo0];
#pragma unroll
      for (int ki = 0; ki < 4; ++ki)
#pragma unroll
        for (int qi = 0; qi < 2; ++qi)
          sacc[ki][qi] = __builtin_amdgcn_mfma_f32_16x16x32_bf16(kf[ki], qf[qi][0], FZ, 0, 0, 0);
#pragma unroll
      for (int ki = 0; ki < 4; ++ki)
        kf[ki] = *(const bf16x8*)&Ks[(ki * 16 + l15) * 64 + Xo1];
#pragma unroll
      for (int ki = 0; ki < 4; ++ki)
#pragma unroll
        for (int qi = 0; qi < 2; ++qi)
          sacc[ki][qi] = __builtin_amdgcn_mfma_f32_16x16x32_bf16(kf[ki], qf[qi][1], sacc[ki][qi], 0, 0, 0);
    }

    // p = 2^s; pack P^T pairs in B-operand order (no VALU row-sums)
    i32x4 pk[2][2];
#pragma unroll
    for (int qi = 0; qi < 2; ++qi)
#pragma unroll
      for (int kc = 0; kc < 2; ++kc)
#pragma unroll
        for (int u = 0; u < 2; ++u) {
          int ki = kc * 2 + u;
          float p0 = __builtin_amdgcn_exp2f(sacc[ki][qi][0]);
          float p1 = __builtin_amdgcn_exp2f(sacc[ki][qi][1]);
          float p2 = __builtin_amdgcn_exp2f(sacc[ki][qi][2]);
          float p3 = __builtin_amdgcn_exp2f(sacc[ki][qi][3]);
          pk[qi][kc][u * 2 + 0] = pkbf16(p0, p1);
          pk[qi][kc][u * 2 + 1] = pkbf16(p2, p3);
        }

    // O^T += V^T * P^T ; l += ones * P^T (row-sum on the MFMA pipe)
#pragma unroll
    for (int kc = 0; kc < 2; ++kc) {
      const int Xo = kc ? Xo1 : Xo0;
      bf16x8 vf[4];
#pragma unroll
      for (int di = 0; di < 4; ++di)
        vf[di] = *(const bf16x8*)&Vs[(di * 16 + l15) * 64 + Xo];
#pragma unroll
      for (int di = 0; di < 4; ++di)
#pragma unroll
        for (int qi = 0; qi < 2; ++qi)
          oacc[di][qi] = __builtin_amdgcn_mfma_f32_16x16x32_bf16(
              vf[di], __builtin_bit_cast(bf16x8, pk[qi][kc]), oacc[di][qi], 0, 0, 0);
#pragma unroll
      for (int qi = 0; qi < 2; ++qi)
        lacc[qi] = __builtin_amdgcn_mfma_f32_16x16x32_bf16(
            ones, __builtin_bit_cast(bf16x8, pk[qi][kc]), lacc[qi], 0, 0, 0);
    }
  }

  // epilogue: O^T/l -> Og[b*2048+q][h*64+d]. Every lane's lacc[qi][*] = l[q=..+l15].
  const int b = bh >> 4, h = bh & 15;
#pragma unroll
  for (int qi = 0; qi < 2; ++qi) {
    float inv = 1.f / lacc[qi][0];
    int q = qt * 128 + wave * 32 + qi * 16 + l15;
#pragma unroll
    for (int di = 0; di < 4; ++di) {
      unsigned int lo = (unsigned int)f2bf(oacc[di][qi][0] * inv) |
                        ((unsigned int)f2bf(oacc[di][qi][1] * inv) << 16);
      unsigned int hi = (unsigned int)f2bf(oacc[di][qi][2] * inv) |
                        ((unsigned int)f2bf(oacc[di][qi][3] * inv) << 16);
      uint2 st; st.x = lo; st.y = hi;
      *(uint2*)(Og + ((size_t)(b * 2048 + q) * 1024) + h * 64 + di * 16 + quad * 4) = st;
    }
  }
}

extern "C" void kernel_launch(void* const* d_in, const int* in_sizes, int n_in,
                              void* d_out, int out_size, void* d_ws, size_t ws_size,
                              hipStream_t stream) {
  const float* x  = (const float*)d_in[0];
  const float* wq = (const float*)d_in[1];
  const float* bq = (const float*)d_in[2];
  const float* wk = (const float*)d_in[3];
  const float* bk = (const float*)d_in[4];
  const float* wv = (const float*)d_in[5];
  const float* bv = (const float*)d_in[6];
  const float* wo = (const float*)d_in[7];
  const float* bo = (const float*)d_in[8];
  char* ws = (char*)d_ws;
  unsigned short* Xb    = (unsigned short*)(ws);                      // 16 MB
  unsigned short* Wqkvt = (unsigned short*)(ws + (16ull << 20));      // 6 MB
  unsigned short* Wot   = (unsigned short*)(ws + (22ull << 20));      // 2 MB
  unsigned short* Qg    = (unsigned short*)(ws + (24ull << 20));      // 16 MB
  unsigned short* Kg    = (unsigned short*)(ws + (40ull << 20));      // 16 MB
  unsigned short* Vtg   = (unsigned short*)(ws + (56ull << 20));      // 16 MB
  unsigned short* Og    = (unsigned short*)(ws + (72ull << 20));      // 16 MB

  pack_all_kernel<<<9216, 256, 0, stream>>>(x, wq, wk, wv, wo, Xb, Wqkvt, Wot);
  gemm_bt_kernel<0><<<dim3(64, 24), 256, 0, stream>>>(Xb, Wqkvt, bq, bk, bv,
                                                      Qg, Kg, Vtg, nullptr);
  attn_kernel<<<1024, 256, 0, stream>>>(Qg, Kg, Vtg, Og);
  gemm_bt_kernel<1><<<dim3(64, 8), 256, 0, stream>>>(Og, Wot, bo, nullptr, nullptr,
                                                     nullptr, nullptr, nullptr,
                                                     (float*)d_out);
}

// Round 5
// 267.885 us; speedup vs baseline: 1.0870x; 1.0870x over previous
//
#include <hip/hip_runtime.h>
#include <cstdint>

// Problem: B=4, S=2048, D_MODEL=1024, H=16, depth=64.
// Pipeline: pack x->bf16 + pack/transpose W->bf16 [N][K] (one launch);
// QKV GEMM (bf16 MFMA, fp32 acc, single-barrier double-buffered K-loop,
// C^T orientation for Q/K -> vectorized stores) -> Q[bh,s,d] (pre-scaled by
// log2e/8), K[bh,s,d], Vt[bh,d,s'] key-permuted; flash attention (no-max
// softmax, P in registers, cross-iteration software pipeline: PV(kt-1)
// overlaps exp2(kt), V triple-buffered in LDS); out GEMM (C^T, float4) -> fp32.

typedef __bf16 bf16x8 __attribute__((ext_vector_type(8)));
typedef float f32x4 __attribute__((ext_vector_type(4)));
typedef int i32x4 __attribute__((ext_vector_type(4)));

#define CEXP 0.18033688011112042f  // (1/8) * log2(e), folded into Q

__device__ __forceinline__ unsigned short f2bf(float f) {
  union { float f; unsigned int u; } v; v.f = f;
  unsigned int r = v.u + 0x7FFFu + ((v.u >> 16) & 1u);  // RNE
  return (unsigned short)(r >> 16);
}
__device__ __forceinline__ unsigned int fbits(float f) {
  union { float f; unsigned int u; } v; v.f = f; return v.u;
}

// pack two f32 -> one int holding (bf16(b)<<16)|bf16(a)
__device__ __forceinline__ int pkbf16(float a, float b) {
#if __has_builtin(__builtin_amdgcn_cvt_pk_bf16_f32)
  auto r = __builtin_amdgcn_cvt_pk_bf16_f32(a, b);  // lo=cvt(a), hi=cvt(b), RNE
  return __builtin_bit_cast(int, r);
#else
  return (int)__builtin_amdgcn_perm(fbits(b) + 0x8000u, fbits(a) + 0x8000u, 0x07060302u);
#endif
}

// async global->LDS, 16B per lane. LDS dest = wave-uniform base + lane*16.
__device__ __forceinline__ void gl_lds16(const void* g, void* l) {
  __builtin_amdgcn_global_load_lds(
      (const __attribute__((address_space(1))) void*)(unsigned long long)g,
      (__attribute__((address_space(3))) void*)(unsigned int)(unsigned long long)l,
      16, 0, 0);
}

// ---------------- pack x (fp32 -> bf16) + pack/transpose weights ----------------
__global__ __launch_bounds__(256) void pack_all_kernel(const float* __restrict__ x,
                                                       const float* __restrict__ wq,
                                                       const float* __restrict__ wk,
                                                       const float* __restrict__ wv,
                                                       const float* __restrict__ wo,
                                                       unsigned short* __restrict__ xb,
                                                       unsigned short* __restrict__ wqkvt,
                                                       unsigned short* __restrict__ wot) {
  int bid = blockIdx.x;
  if (bid < 8192) {  // pack x
    int i = (bid * 256 + threadIdx.x) * 4;
    float4 v = *(const float4*)(x + i);
    unsigned int lo = (unsigned int)f2bf(v.x) | ((unsigned int)f2bf(v.y) << 16);
    unsigned int hi = (unsigned int)f2bf(v.z) | ((unsigned int)f2bf(v.w) << 16);
    uint2 st; st.x = lo; st.y = hi;
    *(uint2*)(xb + i) = st;
    return;
  }
  // pack + transpose weights: Wt[n][k] = w[k][n]
  __shared__ unsigned short T[64 * 66];  // +2 pad: conflict-free
  bid -= 8192;
  int mat = bid >> 8;                    // 0..3 = wq,wk,wv,wo
  int tile = bid & 255;
  int tk = tile >> 4, tn = tile & 15;    // 64x64 tiles
  const float* W = (mat == 0) ? wq : (mat == 1) ? wk : (mat == 2) ? wv : wo;
  int t = threadIdx.x;
#pragma unroll
  for (int p = 0; p < 16; ++p) {
    int e = p * 256 + t;
    int r = e >> 6, c = e & 63;
    T[c * 66 + r] = f2bf(W[(tk * 64 + r) * 1024 + tn * 64 + c]);
  }
  __syncthreads();
  unsigned short* dst = (mat < 3) ? (wqkvt + mat * 1024 * 1024) : wot;
#pragma unroll
  for (int p = 0; p < 16; ++p) {
    int e = p * 256 + t;
    int nn = e >> 6, kk = e & 63;
    dst[(tn * 64 + nn) * 1024 + tk * 64 + kk] = T[nn * 66 + kk];
  }
}

// stage one 128x64 A-tile and 128x64 B-tile (swizzled) via global_load_lds
__device__ __forceinline__ void stage_tile(const unsigned short* __restrict__ Ag,
                                           const unsigned short* __restrict__ Bg,
                                           unsigned short* As, unsigned short* Bs,
                                           int t, int wave) {
#pragma unroll
  for (int p = 0; p < 4; ++p) {
    int s = p * 256 + t;
    int row = s >> 3;
    int cc = (s & 7) ^ (row & 7);
    gl_lds16(Ag + row * 1024 + cc * 8, (void*)(As + (p * 256 + wave * 64) * 8));
    gl_lds16(Bg + row * 1024 + cc * 8, (void*)(Bs + (p * 256 + wave * 64) * 8));
  }
}

// K-loop: acc = A-tile x B-tile^T over K=1024. TRANS=1 computes C^T
// (lane = m-row, regs = 4 consecutive n) for vectorized epilogue stores.
template <int TRANS>
__device__ __forceinline__ void kloop(const unsigned short* __restrict__ Ab,
                                      const unsigned short* __restrict__ Bb,
                                      unsigned short* S, f32x4 acc[4][4],
                                      int t, int wave, int l15, int quad,
                                      int wm, int wn, int Xo0, int Xo1) {
  stage_tile(Ab, Bb, S, S + 8192, t, wave);  // tile 0 -> buf 0
  for (int k0 = 0; k0 < 1024; k0 += 64) {
    const int buf = (k0 >> 6) & 1;
    unsigned short* Sc = S + buf * 16384;
    __syncthreads();  // drains buf's loads (issued one full iteration ago)
    if (k0 < 1024 - 64) {
      unsigned short* Sn = S + (buf ^ 1) * 16384;
      stage_tile(Ab + k0 + 64, Bb + k0 + 64, Sn, Sn + 8192, t, wave);
    }
#pragma unroll
    for (int kc = 0; kc < 2; ++kc) {
      const int Xo = kc ? Xo1 : Xo0;
      bf16x8 af[4], bfr[4];
#pragma unroll
      for (int mi = 0; mi < 4; ++mi)
        af[mi] = *(const bf16x8*)&Sc[(wm * 64 + mi * 16 + l15) * 64 + Xo];
#pragma unroll
      for (int ni = 0; ni < 4; ++ni)
        bfr[ni] = *(const bf16x8*)&Sc[8192 + (wn * 64 + ni * 16 + l15) * 64 + Xo];
#pragma unroll
      for (int mi = 0; mi < 4; ++mi)
#pragma unroll
        for (int ni = 0; ni < 4; ++ni)
          acc[mi][ni] = TRANS
              ? __builtin_amdgcn_mfma_f32_16x16x32_bf16(bfr[ni], af[mi], acc[mi][ni], 0, 0, 0)
              : __builtin_amdgcn_mfma_f32_16x16x32_bf16(af[mi], bfr[ni], acc[mi][ni], 0, 0, 0);
    }
  }
}

// ---------------- GEMM: C[M][N] = A[M][1024] * Bt[N][1024]^T ----------------
// MODE 0: QKV epilogue (bias + scatter bf16 to Q/K/Vt; Q pre-scaled by CEXP;
//         Vt key order permuted within 64-blocks).  MODE 1: fp32 out + bias.
template <int MODE>
__global__ __launch_bounds__(256) void gemm_bt_kernel(
    const unsigned short* __restrict__ A, const unsigned short* __restrict__ Bt,
    const float* __restrict__ b0, const float* __restrict__ b1, const float* __restrict__ b2,
    unsigned short* __restrict__ Qg, unsigned short* __restrict__ Kg,
    unsigned short* __restrict__ Vtg, float* __restrict__ Of) {
  __shared__ __align__(16) unsigned short S[32768];  // 64KB: [buf][A 8192 | B 8192]
  const int t = threadIdx.x;
  const int lane = t & 63, wave = t >> 6;
  const int l15 = lane & 15, quad = lane >> 4;
  const int wm = wave & 1, wn = wave >> 1;
  const int m0 = blockIdx.x * 128, n0 = blockIdx.y * 128;
  const unsigned short* Ab = A + (size_t)m0 * 1024;
  const unsigned short* Bb = Bt + (size_t)n0 * 1024;
  const int seg = (MODE == 0) ? (blockIdx.y >> 3) : 0;  // 0=Q,1=K,2=V

  f32x4 acc[4][4];
#pragma unroll
  for (int i = 0; i < 4; ++i)
#pragma unroll
    for (int j = 0; j < 4; ++j) acc[i][j] = (f32x4){0.f, 0.f, 0.f, 0.f};

  const int Xo0 = ((quad ^ (l15 & 7)) * 8);
  const int Xo1 = (((4 + quad) ^ (l15 & 7)) * 8);

  if (MODE == 1 || seg < 2) {  // block-uniform branch
    kloop<1>(Ab, Bb, S, acc, t, wave, l15, quad, wm, wn, Xo0, Xo1);
    if (MODE == 0) {
      // C^T: lane=m (s row), regs = 4 consecutive n (d) -> 8B stores
      const float* bias = (seg == 0) ? b0 : b1;
      unsigned short* qk = (seg == 0) ? Qg : Kg;
      const int m = m0 + wm * 64 + l15;
#pragma unroll
      for (int mi = 0; mi < 4; ++mi) {
        int mm = m + mi * 16;
        int b = mm >> 11, s = mm & 2047;
        size_t rowoff;
#pragma unroll
        for (int ni = 0; ni < 4; ++ni) {
          int nb = n0 + wn * 64 + ni * 16 + quad * 4;
          int nn = nb & 1023;
          float4 bb = *(const float4*)(bias + nn);
          int h = nn >> 6, d = nn & 63;
          float v0 = acc[mi][ni][0] + bb.x, v1 = acc[mi][ni][1] + bb.y;
          float v2 = acc[mi][ni][2] + bb.z, v3 = acc[mi][ni][3] + bb.w;
          if (seg == 0) { v0 *= CEXP; v1 *= CEXP; v2 *= CEXP; v3 *= CEXP; }
          uint2 st;
          st.x = (unsigned int)pkbf16(v0, v1);
          st.y = (unsigned int)pkbf16(v2, v3);
          *(uint2*)(qk + ((size_t)((b * 16 + h) * 2048 + s)) * 64 + d) = st;
        }
      }
    } else {
      // out-proj: float4 stores to Of[m][n..n+3]
      const int m = m0 + wm * 64 + l15;
#pragma unroll
      for (int mi = 0; mi < 4; ++mi) {
        int mm = m + mi * 16;
#pragma unroll
        for (int ni = 0; ni < 4; ++ni) {
          int n = n0 + wn * 64 + ni * 16 + quad * 4;
          float4 bb = *(const float4*)(b0 + n);
          float4 st;
          st.x = acc[mi][ni][0] + bb.x; st.y = acc[mi][ni][1] + bb.y;
          st.z = acc[mi][ni][2] + bb.z; st.w = acc[mi][ni][3] + bb.w;
          *(float4*)(Of + (size_t)mm * 1024 + n) = st;
        }
      }
    }
  } else {  // V: normal orientation; regs = 4 consecutive permuted key slots
    kloop<0>(Ab, Bb, S, acc, t, wave, l15, quad, wm, wn, Xo0, Xo1);
#pragma unroll
    for (int ni = 0; ni < 4; ++ni) {
      int n = n0 + wn * 64 + ni * 16 + l15;
      int nn = n & 1023;
      int h = nn >> 6, d = nn & 63;
      float bb = b2[nn];
#pragma unroll
      for (int mi = 0; mi < 4; ++mi) {
        int mb = m0 + wm * 64 + mi * 16 + quad * 4;
        int b = mb >> 11, s0 = mb & 2047;
        // key permutation keeps low 2 bits: 4 consecutive slots
        int sp0 = (s0 & ~63) | (s0 & 32) | ((s0 & 12) << 1) | ((s0 & 16) >> 2);
        float v0 = acc[mi][ni][0] + bb, v1 = acc[mi][ni][1] + bb;
        float v2 = acc[mi][ni][2] + bb, v3 = acc[mi][ni][3] + bb;
        uint2 st;
        st.x = (unsigned int)pkbf16(v0, v1);
        st.y = (unsigned int)pkbf16(v2, v3);
        *(uint2*)(Vtg + ((size_t)((b * 16 + h) * 64 + d)) * 2048 + sp0) = st;
      }
    }
  }
}

// ---------------- flash attention (S^T formulation, no-max softmax) ----------------
// grid: 1024 blocks; swizzled to (bh, qt). 4 waves; wave owns 32 q rows.
// Software pipeline: iteration kt computes S(kt)=K*Q^T, then PV(kt-1) MFMAs
// (independent of exp2(kt)) fill the matrix pipe while VALU runs exp2(kt).
// V is triple-buffered in LDS so V(kt-1) survives the prefetch of V(kt+1).
__global__ __launch_bounds__(256) void attn_kernel(const unsigned short* __restrict__ Qg,
                                                   const unsigned short* __restrict__ Kg,
                                                   const unsigned short* __restrict__ Vtg,
                                                   unsigned short* __restrict__ Og) {
  // 40KB: K0@0, K1@4096, V0@8192, V1@12288, V2@16384; Q staged @12288..20479
  __shared__ __align__(16) unsigned short smem[20480];
  const int t = threadIdx.x;
  const int lane = t & 63, wave = t >> 6;
  const int l15 = lane & 15, quad = lane >> 4;
  const int bid = blockIdx.x;
  const int bh = (bid & 7) * 8 + (bid >> 7);  // XCD-affinity: same bh -> same XCD
  const int qt = (bid >> 3) & 15;

  const unsigned short* Qh = Qg + (bh * 2048 + qt * 128) * 64;
  const unsigned short* Kh = Kg + bh * 2048 * 64;
  const unsigned short* Vth = Vtg + bh * 64 * 2048;

  // stage Q (128x64, swizzled) @12288; K tile0 @0; V tile0 @8192
#pragma unroll
  for (int p = 0; p < 4; ++p) {
    int s = p * 256 + t;
    int row = s >> 3, cc = (s & 7) ^ (row & 7);
    gl_lds16(Qh + row * 64 + cc * 8, (void*)(smem + 12288 + (p * 256 + wave * 64) * 8));
  }
#pragma unroll
  for (int p = 0; p < 2; ++p) {
    int s = p * 256 + t;
    int row = s >> 3, cc = (s & 7) ^ (row & 7);
    gl_lds16(Kh + row * 64 + cc * 8, (void*)(smem + (p * 256 + wave * 64) * 8));
    gl_lds16(Vth + row * 2048 + cc * 8, (void*)(smem + 8192 + (p * 256 + wave * 64) * 8));
  }
  __syncthreads();  // Q,K0,V0 resident

  const int Xo0 = ((quad ^ (l15 & 7)) * 8);
  const int Xo1 = (((4 + quad) ^ (l15 & 7)) * 8);

  // loop-invariant Q fragments (B-operand: lane=q, elems=d)
  bf16x8 qf[2][2];
#pragma unroll
  for (int qi = 0; qi < 2; ++qi) {
    qf[qi][0] = *(const bf16x8*)&smem[12288 + (wave * 32 + qi * 16 + l15) * 64 + Xo0];
    qf[qi][1] = *(const bf16x8*)&smem[12288 + (wave * 32 + qi * 16 + l15) * 64 + Xo1];
  }
  __syncthreads();  // all waves done reading Q before V1/V2 overwrite it

  const f32x4 FZ = (f32x4){0.f, 0.f, 0.f, 0.f};
  const int one2 = 0x3F803F80;  // two bf16 1.0
  const i32x4 onesi = (i32x4){one2, one2, one2, one2};
  const bf16x8 ones = __builtin_bit_cast(bf16x8, onesi);

  f32x4 oacc[4][2];
#pragma unroll
  for (int di = 0; di < 4; ++di)
#pragma unroll
    for (int qi = 0; qi < 2; ++qi) oacc[di][qi] = FZ;
  f32x4 lacc[2];
  lacc[0] = FZ; lacc[1] = FZ;

  i32x4 pkP[2][2];  // P^T of tile kt-1 (B-operand packed)
  int kCur = 0, kNxt = 4096;                        // K double-buffer offsets
  int vPrv = 16384, vCur = 8192, vNxt = 12288;      // V triple-buffer offsets

  for (int kt = 0; kt < 32; ++kt) {
    if (kt) __syncthreads();  // drains prefetch issued last iter + LDS reuse
    if (kt < 31) {
      const unsigned short* Kn = Kh + (kt + 1) * 64 * 64;
      const unsigned short* Vn = Vth + (kt + 1) * 64;
#pragma unroll
      for (int p = 0; p < 2; ++p) {
        int s = p * 256 + t;
        int row = s >> 3, cc = (s & 7) ^ (row & 7);
        gl_lds16(Kn + row * 64 + cc * 8, (void*)(smem + kNxt + (p * 256 + wave * 64) * 8));
        gl_lds16(Vn + row * 2048 + cc * 8, (void*)(smem + vNxt + (p * 256 + wave * 64) * 8));
      }
    }
    const unsigned short* Ks = smem + kCur;
    const unsigned short* Vp = smem + vPrv;  // V tile kt-1

    // S^T(kt) = K * Q^T  (kc=0 uses zero C-operand)
    f32x4 sacc[4][2];
    {
      bf16x8 kf[4];
#pragma unroll
      for (int ki = 0; ki < 4; ++ki)
        kf[ki] = *(const bf16x8*)&Ks[(ki * 16 + l15) * 64 + Xo0];
#pragma unroll
      for (int ki = 0; ki < 4; ++ki)
#pragma unroll
        for (int qi = 0; qi < 2; ++qi)
          sacc[ki][qi] = __builtin_amdgcn_mfma_f32_16x16x32_bf16(kf[ki], qf[qi][0], FZ, 0, 0, 0);
#pragma unroll
      for (int ki = 0; ki < 4; ++ki)
        kf[ki] = *(const bf16x8*)&Ks[(ki * 16 + l15) * 64 + Xo1];
#pragma unroll
      for (int ki = 0; ki < 4; ++ki)
#pragma unroll
        for (int qi = 0; qi < 2; ++qi)
          sacc[ki][qi] = __builtin_amdgcn_mfma_f32_16x16x32_bf16(kf[ki], qf[qi][1], sacc[ki][qi], 0, 0, 0);
    }

    // PV(kt-1): independent of exp2(kt) -> fills matrix pipe during exp2
    if (kt > 0) {
#pragma unroll
      for (int kc = 0; kc < 2; ++kc) {
        const int Xo = kc ? Xo1 : Xo0;
        bf16x8 vf[4];
#pragma unroll
        for (int di = 0; di < 4; ++di)
          vf[di] = *(const bf16x8*)&Vp[(di * 16 + l15) * 64 + Xo];
#pragma unroll
        for (int di = 0; di < 4; ++di)
#pragma unroll
          for (int qi = 0; qi < 2; ++qi)
            oacc[di][qi] = __builtin_amdgcn_mfma_f32_16x16x32_bf16(
                vf[di], __builtin_bit_cast(bf16x8, pkP[qi][kc]), oacc[di][qi], 0, 0, 0);
#pragma unroll
        for (int qi = 0; qi < 2; ++qi)
          lacc[qi] = __builtin_amdgcn_mfma_f32_16x16x32_bf16(
              ones, __builtin_bit_cast(bf16x8, pkP[qi][kc]), lacc[qi], 0, 0, 0);
      }
    }

    // exp2(kt) -> pkP (overwrites after PV consumed it; WAR resolved at issue)
#pragma unroll
    for (int qi = 0; qi < 2; ++qi)
#pragma unroll
      for (int kc = 0; kc < 2; ++kc)
#pragma unroll
        for (int u = 0; u < 2; ++u) {
          int ki = kc * 2 + u;
          float p0 = __builtin_amdgcn_exp2f(sacc[ki][qi][0]);
          float p1 = __builtin_amdgcn_exp2f(sacc[ki][qi][1]);
          float p2 = __builtin_amdgcn_exp2f(sacc[ki][qi][2]);
          float p3 = __builtin_amdgcn_exp2f(sacc[ki][qi][3]);
          pkP[qi][kc][u * 2 + 0] = pkbf16(p0, p1);
          pkP[qi][kc][u * 2 + 1] = pkbf16(p2, p3);
        }

    // rotate buffers
    int tmp = kCur; kCur = kNxt; kNxt = tmp;
    tmp = vPrv; vPrv = vCur; vCur = vNxt; vNxt = tmp;
  }

  // tail: PV(31) from V[31%3] (== vPrv after final rotation)
  {
    const unsigned short* Vp = smem + vPrv;
#pragma unroll
    for (int kc = 0; kc < 2; ++kc) {
      const int Xo = kc ? Xo1 : Xo0;
      bf16x8 vf[4];
#pragma unroll
      for (int di = 0; di < 4; ++di)
        vf[di] = *(const bf16x8*)&Vp[(di * 16 + l15) * 64 + Xo];
#pragma unroll
      for (int di = 0; di < 4; ++di)
#pragma unroll
        for (int qi = 0; qi < 2; ++qi)
          oacc[di][qi] = __builtin_amdgcn_mfma_f32_16x16x32_bf16(
              vf[di], __builtin_bit_cast(bf16x8, pkP[qi][kc]), oacc[di][qi], 0, 0, 0);
#pragma unroll
      for (int qi = 0; qi < 2; ++qi)
        lacc[qi] = __builtin_amdgcn_mfma_f32_16x16x32_bf16(
            ones, __builtin_bit_cast(bf16x8, pkP[qi][kc]), lacc[qi], 0, 0, 0);
    }
  }

  // epilogue: O^T/l -> Og[b*2048+q][h*64+d]. Every lane's lacc[qi][*] = l[q].
  const int b = bh >> 4, h = bh & 15;
#pragma unroll
  for (int qi = 0; qi < 2; ++qi) {
    float inv = 1.f / lacc[qi][0];
    int q = qt * 128 + wave * 32 + qi * 16 + l15;
#pragma unroll
    for (int di = 0; di < 4; ++di) {
      unsigned int lo = (unsigned int)f2bf(oacc[di][qi][0] * inv) |
                        ((unsigned int)f2bf(oacc[di][qi][1] * inv) << 16);
      unsigned int hi = (unsigned int)f2bf(oacc[di][qi][2] * inv) |
                        ((unsigned int)f2bf(oacc[di][qi][3] * inv) << 16);
      uint2 st; st.x = lo; st.y = hi;
      *(uint2*)(Og + ((size_t)(b * 2048 + q) * 1024) + h * 64 + di * 16 + quad * 4) = st;
    }
  }
}

extern "C" void kernel_launch(void* const* d_in, const int* in_sizes, int n_in,
                              void* d_out, int out_size, void* d_ws, size_t ws_size,
                              hipStream_t stream) {
  const float* x  = (const float*)d_in[0];
  const float* wq = (const float*)d_in[1];
  const float* bq = (const float*)d_in[2];
  const float* wk = (const float*)d_in[3];
  const float* bk = (const float*)d_in[4];
  const float* wv = (const float*)d_in[5];
  const float* bv = (const float*)d_in[6];
  const float* wo = (const float*)d_in[7];
  const float* bo = (const float*)d_in[8];
  char* ws = (char*)d_ws;
  unsigned short* Xb    = (unsigned short*)(ws);                      // 16 MB
  unsigned short* Wqkvt = (unsigned short*)(ws + (16ull << 20));      // 6 MB
  unsigned short* Wot   = (unsigned short*)(ws + (22ull << 20));      // 2 MB
  unsigned short* Qg    = (unsigned short*)(ws + (24ull << 20));      // 16 MB
  unsigned short* Kg    = (unsigned short*)(ws + (40ull << 20));      // 16 MB
  unsigned short* Vtg   = (unsigned short*)(ws + (56ull << 20));      // 16 MB
  unsigned short* Og    = (unsigned short*)(ws + (72ull << 20));      // 16 MB

  pack_all_kernel<<<9216, 256, 0, stream>>>(x, wq, wk, wv, wo, Xb, Wqkvt, Wot);
  gemm_bt_kernel<0><<<dim3(64, 24), 256, 0, stream>>>(Xb, Wqkvt, bq, bk, bv,
                                                      Qg, Kg, Vtg, nullptr);
  attn_kernel<<<1024, 256, 0, stream>>>(Qg, Kg, Vtg, Og);
  gemm_bt_kernel<1><<<dim3(64, 8), 256, 0, stream>>>(Og, Wot, bo, nullptr, nullptr,
                                                     nullptr, nullptr, nullptr,
                                                     (float*)d_out);
}